// Round 4
// baseline (596.670 us; speedup 1.0000x reference)
//
#include <hip/hip_runtime.h>

#define H 512
#define OW 128
#define NB 16384

typedef float f32x4 __attribute__((ext_vector_type(4)));
typedef short short8 __attribute__((ext_vector_type(8)));
typedef unsigned short ushort8v __attribute__((ext_vector_type(8)));

static __device__ __forceinline__ unsigned short f2bf(float f) {
    union { float f; unsigned u; } v; v.f = f;
    return (unsigned short)((v.u + 0x7FFFu + ((v.u >> 16) & 1u)) >> 16);  // RNE
}

static __device__ __forceinline__ f32x4 mfma16(short8 a, short8 b, f32x4 c) {
    return __builtin_amdgcn_mfma_f32_16x16x32_bf16(a, b, c, 0, 0, 0);
}

// Async 16B/lane global->LDS DMA (linear LDS dest, pre-swizzled global src).
static __device__ __forceinline__ void gll16(const unsigned short* g, unsigned short* l) {
    __builtin_amdgcn_global_load_lds(
        (__attribute__((address_space(1))) void*)g,
        (__attribute__((address_space(3))) void*)l, 16, 0, 0);
}

// Counted-vmcnt barrier (T4): wait own N-newest-may-be-outstanding, then raw
// s_barrier. NO implicit vmcnt(0)/lgkmcnt(0) drain (that drain is the m97
// ceiling). memory clobber = compiler fence so gll16/ds ops can't cross.
#define WAITB(n) asm volatile("s_waitcnt vmcnt(" #n ")\n\ts_barrier" ::: "memory")
#define RELB()   asm volatile("s_barrier" ::: "memory")
#define CFENCE() asm volatile("" ::: "memory")

// ---- prep: weights transpose+cast, x cast ----
__global__ void prep_w1(const float* __restrict__ share_W1,
                        const float* __restrict__ task_W1,
                        unsigned short* __restrict__ w1t) {
    const int inst = blockIdx.z;
    const float* src = (inst < 5) ? (share_W1 + (size_t)inst * H * H)
                                  : (task_W1 + (size_t)(inst - 5) * H * H);
    unsigned short* dst = w1t + (size_t)inst * H * H;
    const int g = blockIdx.x * 256 + threadIdx.x;
    const int n = g & (H - 1);
    const int kc = g >> 9;
    float v[8];
#pragma unroll
    for (int i = 0; i < 8; ++i) v[i] = src[(size_t)(kc * 8 + i) * H + n];
    ushort8v o;
#pragma unroll
    for (int i = 0; i < 8; ++i) o[i] = f2bf(v[i]);
    *(ushort8v*)&dst[(size_t)n * H + kc * 8] = o;
}

// W2 -> fragment-linear layout for direct-to-register b128 loads in gemm2:
// w2f[inst][nt][wx][kk*4+j][lane][8] ; element = W2[k][n] with
// n = wx*64 + j*16 + (lane&15), k = nt*128 + kk*32 + (lane>>4)*8 + i.
__global__ void prep_w2(const float* __restrict__ share_W2,
                        const float* __restrict__ task_W2,
                        unsigned short* __restrict__ w2f) {
    const int inst = blockIdx.z;
    const float* src = (inst < 5) ? (share_W2 + (size_t)inst * H * OW)
                                  : (task_W2 + (size_t)(inst - 5) * H * OW);
    unsigned short* dst = w2f + (size_t)inst * H * OW;
    const int g = blockIdx.x * 256 + threadIdx.x;   // 0..8191
    const int l  = g & 63;
    const int f  = (g >> 6) & 15;
    const int kk = f >> 2, j = f & 3;
    const int wx = (g >> 10) & 1;
    const int nt = (g >> 11) & 3;
    const int n  = wx * 64 + j * 16 + (l & 15);
    const int k0 = nt * 128 + kk * 32 + ((l >> 4) & 3) * 8;
    float v[8];
#pragma unroll
    for (int i = 0; i < 8; ++i) v[i] = src[(size_t)(k0 + i) * OW + n];
    ushort8v o;
#pragma unroll
    for (int i = 0; i < 8; ++i) o[i] = f2bf(v[i]);
    *(ushort8v*)&dst[(size_t)g * 8] = o;
}

__global__ void prep_x(const float* __restrict__ x0, const float* __restrict__ x1,
                       const float* __restrict__ x2, unsigned short* __restrict__ xb) {
    const int z = blockIdx.z;
    const float* s = (z == 0) ? x0 : (z == 1 ? x1 : x2);
    const size_t g = (size_t)(blockIdx.x * 256 + threadIdx.x) * 8;
    float4 a = *(const float4*)&s[g];
    float4 b = *(const float4*)&s[g + 4];
    ushort8v o;
    o[0] = f2bf(a.x); o[1] = f2bf(a.y); o[2] = f2bf(a.z); o[3] = f2bf(a.w);
    o[4] = f2bf(b.x); o[5] = f2bf(b.y); o[6] = f2bf(b.z); o[7] = f2bf(b.w);
    *(ushort8v*)&xb[(size_t)z * NB * H + g] = o;
}

// ---- fused, pipelined: out = relu(x@W1+b1)@W2 + b2 ----
// grid 1920 = 3z*5e*128rt. 128-row tile, one expert per block.
// kt-loop: BK=32, double-buffered sA/sB, counted vmcnt (20,20,4..4,[4|0]),
// raw asm barriers (no drain). kt+2 staged after release barrier; next-nt
// kt0/kt1 staged at iters 14/15 tails (fly under epilogue+gemm2).
// W2 fragments live in registers (rW2[16], coalesced b128 from w2f).
// LDS: sA dbuf 16K | sB dbuf 16K | sH [128][136] 34.8K = 67.6K -> 2 blk/CU.
__global__ __launch_bounds__(256, 2) void fused(
    const unsigned short* __restrict__ xb, const unsigned short* __restrict__ w1t,
    const unsigned short* __restrict__ w2f,
    const float* __restrict__ share_b1, const float* __restrict__ task_b1,
    const float* __restrict__ share_b2, const float* __restrict__ task_b2,
    float* __restrict__ out)
{
    __shared__ unsigned short smem[33792];      // 67.6 KB
    // sA[buf] = smem + buf*4096 ; sB[buf] = smem + 8192 + buf*4096 ; each [128][32]
    unsigned short* sH = smem + 16384;          // [128][136] bf16 h_chunk

    const int tid = threadIdx.x;
    const int lane = tid & 63;
    const int wave = tid >> 6;
    const int wy = wave >> 1, wx = wave & 1;
    const int lm = lane & 15, lq = lane >> 4;
    const int r4 = lane >> 2;                   // 0..15 row-in-group
    const int c4 = lane & 3;
    const int sc4 = c4 ^ (r4 & 3);              // pre-swizzled source chunk (BK=32)

    // XCD-bijective swizzle: 1920 % 8 == 0; e fastest -> experts sharing an
    // x rowtile are L2-co-resident on one XCD.
    const int swz = (blockIdx.x & 7) * 240 + (blockIdx.x >> 3);
    const int z = swz / 640;
    const int rzi = swz % 640;
    const int rowtile = rzi / 5;
    const int e = rzi % 5;
    const int inst = z * 5 + e;

    const unsigned short* xp  = xb + ((size_t)z * NB + rowtile * 128) * H;
    const unsigned short* w1p = w1t + (size_t)inst * H * H;
    const unsigned short* w2b = w2f + (size_t)inst * H * OW + (size_t)lane * 8;
    const float* b1 = (z == 0) ? (share_b1 + e * H) : (task_b1 + ((z - 1) * 5 + e) * H);
    const float* b2 = (z == 0) ? (share_b2 + e * OW) : (task_b2 + ((z - 1) * 5 + e) * OW);
    float* op = out + ((size_t)inst * NB + rowtile * 128) * OW;

    const f32x4 zero4 = {0.f, 0.f, 0.f, 0.f};
    f32x4 acc2[4][4];
#pragma unroll
    for (int i = 0; i < 4; ++i)
#pragma unroll
        for (int j = 0; j < 4; ++j) acc2[i][j] = zero4;

    f32x4 acc1[4][4];

    // stage one BK=32 tile-pair (4 gll16/wave) for (nt,kt) into buf
    auto STAGE = [&](int kt, int buf, const unsigned short* wsrc) {
        unsigned short* a = smem + buf * 4096;
        unsigned short* b = smem + 8192 + buf * 4096;
        const int ko = kt * 32 + sc4 * 8;
#pragma unroll
        for (int t = 0; t < 2; ++t) {
            gll16(&xp  [(size_t)(wave * 32 + t * 16 + r4) * H + ko], &a[wave * 1024 + t * 512]);
            gll16(&wsrc[(size_t)(wave * 32 + t * 16 + r4) * H + ko], &b[wave * 1024 + t * 512]);
        }
    };

    auto COMPUTE = [&](int buf) {
        const unsigned short* a = smem + buf * 4096;
        const unsigned short* b = smem + 8192 + buf * 4096;
        const int sw = (lq ^ (lm & 3)) << 3;
        short8 af[4], bq[4];
#pragma unroll
        for (int i = 0; i < 4; ++i) af[i] = *(const short8*)&a[(wy * 64 + i * 16 + lm) * 32 + sw];
#pragma unroll
        for (int j = 0; j < 4; ++j) bq[j] = *(const short8*)&b[(wx * 64 + j * 16 + lm) * 32 + sw];
        __builtin_amdgcn_s_setprio(1);
#pragma unroll
        for (int i = 0; i < 4; ++i)
#pragma unroll
            for (int j = 0; j < 4; ++j) acc1[i][j] = mfma16(af[i], bq[j], acc1[i][j]);
        __builtin_amdgcn_s_setprio(0);
    };

    // prologue: nt=0 kt0/kt1 in flight before anything else
    STAGE(0, 0, w1p);
    STAGE(1, 1, w1p);

    for (int nt = 0; nt < 4; ++nt) {
        const unsigned short* wnp = w1p + (size_t)(nt * 128) * H;
        const unsigned short* wnx = w1p + (size_t)(((nt + 1) & 3) * 128) * H;

        // W2 fragments for this nt -> registers (fenced so the 16 loads sit
        // exactly here in the vmem stream: [kt0][kt1][rW2]...).
        CFENCE();
        short8 rW2[16];
        {
            const unsigned short* wb = w2b + (size_t)(nt * 2 + wx) * 16 * 512;
#pragma unroll
            for (int f = 0; f < 16; ++f) rW2[f] = *(const short8*)&wb[f * 512];
        }
        CFENCE();

#pragma unroll
        for (int i = 0; i < 4; ++i)
#pragma unroll
            for (int j = 0; j < 4; ++j) acc1[i][j] = zero4;

        // ---- pipelined kt-loop: K=512, 16 steps of 32 ----
        WAITB(20); COMPUTE(0); RELB(); STAGE(2, 0, wnp);      // kt=0
        WAITB(20); COMPUTE(1); RELB(); STAGE(3, 1, wnp);      // kt=1
        for (int kt = 2; kt < 14; ++kt) {
            WAITB(4); COMPUTE(kt & 1); RELB(); STAGE(kt + 2, kt & 1, wnp);
        }
        WAITB(4); COMPUTE(0); RELB();                          // kt=14
        if (nt < 3) STAGE(0, 0, wnx);                          // next-nt kt0
        if (nt < 3) { WAITB(4); } else { WAITB(0); }           // kt=15
        COMPUTE(1); RELB();
        if (nt < 3) STAGE(1, 1, wnx);                          // next-nt kt1

        // ---- epilogue gemm1: +b1, relu, bf16 -> sH[128][136] ----
#pragma unroll
        for (int j = 0; j < 4; ++j) {
            const int col = wx * 64 + j * 16 + lm;
            const float b1v = b1[nt * 128 + col];
#pragma unroll
            for (int i = 0; i < 4; ++i)
#pragma unroll
                for (int rr = 0; rr < 4; ++rr) {
                    const int row = wy * 64 + i * 16 + lq * 4 + rr;
                    sH[row * 136 + col] = f2bf(fmaxf(acc1[i][j][rr] + b1v, 0.f));
                }
        }
        asm volatile("s_waitcnt lgkmcnt(0)\n\ts_barrier" ::: "memory");

        // ---- gemm2: acc2 += h_chunk @ W2_chunk (k=128), B from registers ----
#pragma unroll
        for (int kk = 0; kk < 4; ++kk) {
            short8 ah[4];
#pragma unroll
            for (int i = 0; i < 4; ++i)
                ah[i] = *(const short8*)&sH[(wy * 64 + i * 16 + lm) * 136 + kk * 32 + lq * 8];
            __builtin_amdgcn_s_setprio(1);
#pragma unroll
            for (int i = 0; i < 4; ++i)
#pragma unroll
                for (int j = 0; j < 4; ++j) acc2[i][j] = mfma16(ah[i], rW2[kk * 4 + j], acc2[i][j]);
            __builtin_amdgcn_s_setprio(0);
        }
    }

    // ---- final epilogue: out = acc2 + b2 (fp32) ----
#pragma unroll
    for (int j = 0; j < 4; ++j) {
        const int col = wx * 64 + j * 16 + lm;
        const float b2v = b2[col];
#pragma unroll
        for (int i = 0; i < 4; ++i)
#pragma unroll
            for (int rr = 0; rr < 4; ++rr) {
                const int row = wy * 64 + i * 16 + lq * 4 + rr;
                op[(size_t)row * OW + col] = acc2[i][j][rr] + b2v;
            }
    }
}

extern "C" void kernel_launch(void* const* d_in, const int* in_sizes, int n_in,
                              void* d_out, int out_size, void* d_ws, size_t ws_size,
                              hipStream_t stream) {
    const float* share_x  = (const float*)d_in[0];
    const float* task_x0  = (const float*)d_in[1];
    const float* task_x1  = (const float*)d_in[2];
    const float* share_W1 = (const float*)d_in[3];
    const float* share_b1 = (const float*)d_in[4];
    const float* share_W2 = (const float*)d_in[5];
    const float* share_b2 = (const float*)d_in[6];
    const float* task_W1  = (const float*)d_in[7];
    const float* task_b1  = (const float*)d_in[8];
    const float* task_W2  = (const float*)d_in[9];
    const float* task_b2  = (const float*)d_in[10];
    float* out = (float*)d_out;

    // ws layout (60.2 MB): w1t 7.86M | w2f 1.97M | xb 50.3M
    unsigned short* w1t = (unsigned short*)d_ws;
    unsigned short* w2f = w1t + (size_t)15 * H * H;
    unsigned short* xb  = w2f + (size_t)15 * OW * H;

    prep_w1<<<dim3(128, 1, 15), 256, 0, stream>>>(share_W1, task_W1, w1t);
    prep_w2<<<dim3(32, 1, 15), 256, 0, stream>>>(share_W2, task_W2, w2f);
    prep_x <<<dim3(4096, 1, 3), 256, 0, stream>>>(share_x, task_x0, task_x1, xb);
    fused<<<1920, 256, 0, stream>>>(xb, w1t, w2f, share_b1, task_b1,
                                    share_b2, task_b2, out);
}